// Round 3
// baseline (42.084 us; speedup 1.0000x reference)
//
#include <hip/hip_runtime.h>
#include <math.h>

// SMEFTNet forward, lanes-over-i layout. B=128, N=128, H=16.
//
// K1 (conv0 + fused proj for conv1): grid 256 = (batch, ihalf), 256 thr = 4 j-quarter waves.
//   Each lane owns node i = ihalf*64+lane; loops over its wave's 32 j's with
//   j-data broadcast from LDS. A-partials merged across the 4 waves via LDS
//   (channel-major, stride-1 = conflict-free). Epilogue per-lane: second MLP
//   layer m = A@w1*invdeg+b1, rotation ang1, proj u1 = b0'+h1@(Wa-Wc),
//   v1 = h1@(Wb+Wc) split across waves.
// K2 (conv1 + partial readout): same shape; j-data = (ang1, inv) + v1[16] in LDS.
//   Wave 0 tail: per-block partial sums (Σptf, Σptf*y[18]) via DPP wave-reduce.
// K3 (readout): 128 blocks × 64 thr; combine 2 partials, 16->32->32->1 MLP.

#define BB 128
#define NN 128
#define BN (BB * NN)

template <int CTRL>
__device__ __forceinline__ float dpp_add(float x) {
    int t = __builtin_amdgcn_update_dpp(0, __float_as_int(x), CTRL, 0xF, 0xF, true);
    return x + __int_as_float(t);
}

// Sum across 64 lanes; returns wave-uniform value.
__device__ __forceinline__ float wave_sum64(float x) {
    x = dpp_add<0xB1>(x);   // quad_perm [1,0,3,2]
    x = dpp_add<0x4E>(x);   // quad_perm [2,3,0,1]
    x = dpp_add<0x114>(x);  // row_shr:4
    x = dpp_add<0x118>(x);  // row_shr:8
    x = dpp_add<0x142>(x);  // row_bcast15
    x = dpp_add<0x143>(x);  // row_bcast31
    return __int_as_float(__builtin_amdgcn_readlane(__float_as_int(x), 63));
}

// ---------------- K1: conv0 + proj for conv1 ----------------
__global__ __launch_bounds__(256) void conv0_kernel(
    const float* __restrict__ ang,   // (B,N,2)
    const float* __restrict__ w0,    // c0_w0 (5,16)
    const float* __restrict__ b0,    // (16)
    const float* __restrict__ w1,    // c0_w1 (16,17)
    const float* __restrict__ b1,    // (17)
    const float* __restrict__ nw0,   // c1_w0 (50,16)
    const float* __restrict__ nb0,   // c1_b0 (16)
    float* __restrict__ ang1,        // (BN,2)
    float* __restrict__ u1,          // (BN,16)
    float* __restrict__ v1)          // (BN,16)
{
    const int tid  = threadIdx.x;
    const int lane = tid & 63;
    const int wid  = tid >> 6;
    const int b     = blockIdx.x >> 1;
    const int ihalf = blockIdx.x & 1;
    const int nodebase = b * NN;
    const int ni = nodebase + ihalf * 64 + lane;

    __shared__ float4 jdat[NN];           // (rej, imj, abszj, invj)
    __shared__ float Ap[4][17][64];       // channel-major partials + deg

    if (tid < NN) {
        float2 a = ((const float2*)ang)[nodebase + tid];
        float r2 = a.x * a.x + a.y * a.y;
        float absz = __builtin_amdgcn_sqrtf(r2);
        float inv = __builtin_amdgcn_rsqf(r2);
        jdat[tid] = make_float4(a.x, a.y, absz, inv);
    }
    __syncthreads();

    const float4 my = jdat[ihalf * 64 + lane];
    const float rei = my.x, imi = my.y, abszi = my.z, invi = my.w;

    // per-lane layer-0 row precompute (uniform weights -> s_load)
    float u0b[16], q0[16];
    #pragma unroll
    for (int k = 0; k < 16; ++k) {
        u0b[k] = fmaf(abszi, w0[k] - w0[32 + k], b0[k]);  // absz*(Wa-Wc)+b0
        q0[k]  = w0[16 + k] + w0[32 + k];                 // Wb+Wc
    }

    float A[16];
    #pragma unroll
    for (int k = 0; k < 16; ++k) A[k] = 0.0f;
    float degf = 0.0f;

    const int jbase = wid * 32;
    float4 cd = jdat[jbase];
    #pragma unroll 2
    for (int jj = 0; jj < 32; ++jj) {
        float4 nd = jdat[jbase + ((jj + 1) & 31)];
        const float rej = cd.x, imj = cd.y, abszj = cd.z, invj = cd.w;
        float dre = rei - rej, dim = imi - imj;
        float d2 = fmaf(dre, dre, dim * dim);
        float adjf = (d2 <= 0.16f) ? 1.0f : 0.0f;
        degf += adjf;
        float inv = invi * invj;
        float cosv = fmaf(rei, rej, imi * imj) * inv;
        float sinv = fmaf(imi, rej, -(rei * imj)) * inv;
        #pragma unroll
        for (int k = 0; k < 16; ++k) {
            float z = fmaf(abszj, q0[k], u0b[k]);
            z = fmaf(cosv, w0[48 + k], z);
            z = fmaf(sinv, w0[64 + k], z);
            float a = fmaxf(z, 0.01f * z);
            A[k] = fmaf(a, adjf, A[k]);
        }
        cd = nd;
    }

    // cross-wave partial merge (channel-major: stride-1 over lanes, no conflicts)
    #pragma unroll
    for (int k = 0; k < 16; ++k) Ap[wid][k][lane] = A[k];
    Ap[wid][16][lane] = degf;
    __syncthreads();
    #pragma unroll
    for (int w2 = 0; w2 < 4; ++w2) {
        if (w2 == wid) continue;
        #pragma unroll
        for (int k = 0; k < 16; ++k) A[k] += Ap[w2][k][lane];
        degf += Ap[w2][16][lane];
    }

    // second MLP layer per lane
    const float invdeg = __builtin_amdgcn_rcpf(degf);
    float m[17];
    #pragma unroll
    for (int t = 0; t < 17; ++t) {
        float s = 0.0f;
        #pragma unroll
        for (int k = 0; k < 16; ++k) s = fmaf(A[k], w1[k * 17 + t], s);
        m[t] = fmaf(s, invdeg, b1[t]);
    }

    if (wid == 0) {  // rotated angles for conv1
        float g = m[16] - floorf(m[16]);
        float cs = __builtin_amdgcn_cosf(g);
        float sn = __builtin_amdgcn_sinf(g);
        float re2 = cs * rei - sn * imi;
        float im2 = fmaf(sn, rei, cs * imi);
        ((float2*)ang1)[ni] = make_float2(re2, im2);
    }

    // proj for conv1, split across waves: wid 0/1 -> u1 halves, 2/3 -> v1 halves
    const int isV = wid >> 1;
    const int khalf = wid & 1;
    float acc[8];
    if (isV == 0) {
        #pragma unroll
        for (int kk = 0; kk < 8; ++kk) {
            const int kp = khalf * 8 + kk;
            float a = nb0[kp];
            #pragma unroll
            for (int c = 0; c < 16; ++c) {
                a = fmaf(m[c], nw0[c * 16 + kp], a);          // +Wa
                a = fmaf(-m[c], nw0[512 + c * 16 + kp], a);   // -Wc
            }
            acc[kk] = a;
        }
        float4* up = (float4*)(u1 + (size_t)ni * 16);
        up[khalf * 2 + 0] = make_float4(acc[0], acc[1], acc[2], acc[3]);
        up[khalf * 2 + 1] = make_float4(acc[4], acc[5], acc[6], acc[7]);
    } else {
        #pragma unroll
        for (int kk = 0; kk < 8; ++kk) {
            const int kp = khalf * 8 + kk;
            float a = 0.0f;
            #pragma unroll
            for (int c = 0; c < 16; ++c) {
                a = fmaf(m[c], nw0[256 + c * 16 + kp], a);    // +Wb
                a = fmaf(m[c], nw0[512 + c * 16 + kp], a);    // +Wc
            }
            acc[kk] = a;
        }
        float4* vp = (float4*)(v1 + (size_t)ni * 16);
        vp[khalf * 2 + 0] = make_float4(acc[0], acc[1], acc[2], acc[3]);
        vp[khalf * 2 + 1] = make_float4(acc[4], acc[5], acc[6], acc[7]);
    }
}

// ---------------- K2: conv1 + partial readout ----------------
__global__ __launch_bounds__(256) void conv1_kernel(
    const float* __restrict__ pt,    // (B,N)
    const float* __restrict__ ang1,  // (BN,2)
    const float* __restrict__ u1,    // (BN,16)
    const float* __restrict__ v1,    // (BN,16)
    const float* __restrict__ w0,    // c1_w0 (50,16) (for cos/sin rows)
    const float* __restrict__ w1,    // c1_w1 (16,17)
    const float* __restrict__ b1,    // (17)
    float* __restrict__ part)        // (256,20): [0]=Σptf, [1..18]=Σptf*y
{
    const int tid  = threadIdx.x;
    const int lane = tid & 63;
    const int wid  = tid >> 6;
    const int b     = blockIdx.x >> 1;
    const int ihalf = blockIdx.x & 1;
    const int nodebase = b * NN;
    const int ni = nodebase + ihalf * 64 + lane;

    __shared__ float4 jdat[NN];      // (rej, imj, invj, -)
    __shared__ float4 jv[NN][4];     // v1[j][16]
    __shared__ float Ap[4][17][64];

    if (tid < NN) {
        float2 a = ((const float2*)ang1)[nodebase + tid];
        float r2 = a.x * a.x + a.y * a.y;
        float inv = __builtin_amdgcn_rsqf(r2);
        jdat[tid] = make_float4(a.x, a.y, inv, 0.0f);
        const float4* vg = (const float4*)(v1 + (size_t)(nodebase + tid) * 16);
        jv[tid][0] = vg[0]; jv[tid][1] = vg[1];
        jv[tid][2] = vg[2]; jv[tid][3] = vg[3];
    }

    // per-lane i data
    float u0b[16];
    {
        const float4* ug = (const float4*)(u1 + (size_t)ni * 16);
        float4 a0 = ug[0], a1 = ug[1], a2 = ug[2], a3 = ug[3];
        u0b[0] = a0.x; u0b[1] = a0.y; u0b[2]  = a0.z; u0b[3]  = a0.w;
        u0b[4] = a1.x; u0b[5] = a1.y; u0b[6]  = a1.z; u0b[7]  = a1.w;
        u0b[8] = a2.x; u0b[9] = a2.y; u0b[10] = a2.z; u0b[11] = a2.w;
        u0b[12] = a3.x; u0b[13] = a3.y; u0b[14] = a3.z; u0b[15] = a3.w;
    }
    float ptf = 0.0f;
    if (wid == 0) ptf = pt[ni];
    __syncthreads();

    const float4 my = jdat[ihalf * 64 + lane];
    const float rei = my.x, imi = my.y, invi = my.z;

    float A[16];
    #pragma unroll
    for (int k = 0; k < 16; ++k) A[k] = 0.0f;
    float degf = 0.0f;

    const int jbase = wid * 32;
    float4 cd = jdat[jbase];
    float4 c0 = jv[jbase][0], c1 = jv[jbase][1], c2 = jv[jbase][2], c3 = jv[jbase][3];
    #pragma unroll 2
    for (int jj = 0; jj < 32; ++jj) {
        const int nj = jbase + ((jj + 1) & 31);
        float4 nd = jdat[nj];
        float4 n0 = jv[nj][0], n1 = jv[nj][1], n2 = jv[nj][2], n3 = jv[nj][3];
        const float rej = cd.x, imj = cd.y, invj = cd.z;
        float dre = rei - rej, dim = imi - imj;
        float d2 = fmaf(dre, dre, dim * dim);
        float adjf = (d2 <= 0.16f) ? 1.0f : 0.0f;
        degf += adjf;
        float inv = invi * invj;
        float cosv = fmaf(rei, rej, imi * imj) * inv;
        float sinv = fmaf(imi, rej, -(rei * imj)) * inv;
        const float vj[16] = {c0.x, c0.y, c0.z, c0.w, c1.x, c1.y, c1.z, c1.w,
                              c2.x, c2.y, c2.z, c2.w, c3.x, c3.y, c3.z, c3.w};
        #pragma unroll
        for (int k = 0; k < 16; ++k) {
            float z = u0b[k] + vj[k];
            z = fmaf(cosv, w0[768 + k], z);
            z = fmaf(sinv, w0[784 + k], z);
            float a = fmaxf(z, 0.01f * z);
            A[k] = fmaf(a, adjf, A[k]);
        }
        cd = nd; c0 = n0; c1 = n1; c2 = n2; c3 = n3;
    }

    #pragma unroll
    for (int k = 0; k < 16; ++k) Ap[wid][k][lane] = A[k];
    Ap[wid][16][lane] = degf;
    __syncthreads();

    if (wid == 0) {
        #pragma unroll
        for (int w2 = 1; w2 < 4; ++w2) {
            #pragma unroll
            for (int k = 0; k < 16; ++k) A[k] += Ap[w2][k][lane];
            degf += Ap[w2][16][lane];
        }
        const float invdeg = __builtin_amdgcn_rcpf(degf);
        float m[17];
        #pragma unroll
        for (int t = 0; t < 17; ++t) {
            float s = 0.0f;
            #pragma unroll
            for (int k = 0; k < 16; ++k) s = fmaf(A[k], w1[k * 17 + t], s);
            m[t] = fmaf(s, invdeg, b1[t]);
        }
        float g = m[16] - floorf(m[16]);
        float cs = __builtin_amdgcn_cosf(g);
        float sn = __builtin_amdgcn_sinf(g);
        float re2 = cs * rei - sn * imi;
        float im2 = fmaf(sn, rei, cs * imi);

        float* pout = part + (size_t)blockIdx.x * 20;
        float s0 = wave_sum64(ptf);
        if (lane == 0) pout[0] = s0;
        #pragma unroll
        for (int f = 0; f < 16; ++f) {
            float sf = wave_sum64(ptf * m[f]);
            if (lane == 0) pout[1 + f] = sf;
        }
        float sre = wave_sum64(ptf * re2);
        float sim = wave_sum64(ptf * im2);
        if (lane == 0) { pout[17] = sre; pout[18] = sim; }
    }
}

// ---------------- K3: final readout ----------------
__global__ __launch_bounds__(64) void readout_kernel(
    const float* __restrict__ part,  // (256,20)
    const float* __restrict__ w0, const float* __restrict__ b0,  // (16,32),(32)
    const float* __restrict__ w1, const float* __restrict__ b1,  // (32,32),(32)
    const float* __restrict__ w2, const float* __restrict__ b2,  // (32,1),(1)
    float* __restrict__ out) {
    const int b = blockIdx.x;
    const int t = threadIdx.x;
    const float* p0 = part + (size_t)(2 * b) * 20;
    const float* p1 = p0 + 20;

    __shared__ float xg[18];
    __shared__ float h1s[32];

    float denom = p0[0] + p1[0];
    float invd = (denom > 0.0f) ? __builtin_amdgcn_rcpf(denom) : 0.0f;
    if (t < 18) xg[t] = (p0[1 + t] + p1[1 + t]) * invd;
    __syncthreads();

    if (t < 32) {
        float h = b0[t];
        #pragma unroll
        for (int k = 0; k < 16; ++k) h = fmaf(xg[k], w0[k * 32 + t], h);
        h = fmaxf(h, 0.01f * h);
        h1s[t] = h;
    }
    __syncthreads();
    if (t < 32) {
        float h = b1[t];
        #pragma unroll
        for (int k = 0; k < 32; ++k) h = fmaf(h1s[k], w1[k * 32 + t], h);
        h = fmaxf(h, 0.01f * h);
        float p = h * w2[t];
        #pragma unroll
        for (int off = 16; off; off >>= 1) p += __shfl_xor(p, off, 32);
        if (t == 0) {
            out[b * 3 + 0] = 1.0f / (1.0f + expf(-(p + b2[0])));
            out[b * 3 + 1] = xg[16];
            out[b * 3 + 2] = xg[17];
        }
    }
}

extern "C" void kernel_launch(void* const* d_in, const int* in_sizes, int n_in,
                              void* d_out, int out_size, void* d_ws, size_t ws_size,
                              hipStream_t stream) {
    const float* pt    = (const float*)d_in[0];
    const float* ang   = (const float*)d_in[1];
    const float* c0_w0 = (const float*)d_in[2];
    const float* c0_b0 = (const float*)d_in[3];
    const float* c0_w1 = (const float*)d_in[4];
    const float* c0_b1 = (const float*)d_in[5];
    const float* c1_w0 = (const float*)d_in[6];
    const float* c1_b0 = (const float*)d_in[7];
    const float* c1_w1 = (const float*)d_in[8];
    const float* c1_b1 = (const float*)d_in[9];
    const float* r_w0  = (const float*)d_in[10];
    const float* r_b0  = (const float*)d_in[11];
    const float* r_w1  = (const float*)d_in[12];
    const float* r_b1  = (const float*)d_in[13];
    const float* r_w2  = (const float*)d_in[14];
    const float* r_b2  = (const float*)d_in[15];
    float* out = (float*)d_out;
    float* ws = (float*)d_ws;

    float* ang1 = ws;                          // BN*2
    float* u1   = ang1 + (size_t)BN * 2;       // BN*16
    float* v1   = u1 + (size_t)BN * 16;        // BN*16
    float* partb = v1 + (size_t)BN * 16;       // 256*20

    hipLaunchKernelGGL(conv0_kernel, dim3(256), dim3(256), 0, stream,
                       ang, c0_w0, c0_b0, c0_w1, c0_b1, c1_w0, c1_b0,
                       ang1, u1, v1);
    hipLaunchKernelGGL(conv1_kernel, dim3(256), dim3(256), 0, stream,
                       pt, ang1, u1, v1, c1_w0, c1_w1, c1_b1, partb);
    hipLaunchKernelGGL(readout_kernel, dim3(BB), dim3(64), 0, stream,
                       partb, r_w0, r_b0, r_w1, r_b1, r_w2, r_b2, out);
}